// Round 9
// baseline (461.023 us; speedup 1.0000x reference)
//
#include <hip/hip_runtime.h>

// DISCO S2 conv, round 15: int8 x with per-row scale (replaces round-14's fp8,
// which failed absmax 1.76e-2 > 1.30e-2; int8+row-scale has 0.37x the quant
// noise -> predicted ~8e-3). Gather structure = round 14: one ds_read_b128 per
// tap covers all 64 c (16 int8/lane), 24 reads/k/wave (was 48 at f16), LDS
// 70.7 KB -> 2 blocks/CU.
// Dequant: u8 (=q+128) -> f16 via v_perm_b32 (0x6400+u = 1024+u exact) ->
// pk_add -1152 (= q exact) -> v_pk_fma_f16 with psi*s broadcast (prep-packed
// f16x2 in meta, per batch). acc f16x8 feeds mfma directly.
// scale_kernel (new, ~0.5us): s[b][lat] = max|x[b,:,lat,:]|/127.

#define NB    2
#define CIN   64
#define COUT  64
#define KS    9
#define NLAT  181
#define NLON  360
#define NPER  24

typedef _Float16 f16;
typedef _Float16 f16x8 __attribute__((ext_vector_type(8)));
typedef float    f32x4 __attribute__((ext_vector_type(4)));
typedef unsigned int u32;
typedef unsigned short u16;
typedef unsigned char u8;
typedef u32 u32x4 __attribute__((ext_vector_type(4)));

#define ROWB8     23040                                   // 360*64 B per lat row
#define SLOTB     23552                                   // padded LDS slot stride
#define XT8_BYTES ((size_t)NB * NLAT * ROWB8)             // 8,340,480
#define WT_BYTES  (KS * 64 * 64 * 2)                      // 73,728
#define NMETA     (KS * NLAT * NPER)                      // 39,096
#define META_BYTES ((size_t)NMETA * 16)
#define XS_BYTES  (3 * SLOTB)                             // 70,656 B LDS

#define U0  (NB * NLAT * 90 * 8)                          // 260,640 threads
#define G0  ((U0 + 255) / 256)                            // 1019
#define G1  ((KS * 4096 + 255) / 256)                     // 144
#define G2  ((NMETA + 255) / 256)                         // 153

#define SEL_LO 0x05010400u
#define SEL_HI 0x05030402u

__device__ __forceinline__ u32 bperm(u32 s0, u32 s1, u32 sel) {
#if __has_builtin(__builtin_amdgcn_perm)
    return __builtin_amdgcn_perm(s0, s1, sel);
#else
    u32 r = 0;
#pragma unroll
    for (int i = 0; i < 4; ++i) {
        u32 code = (sel >> (8 * i)) & 0xffu;
        u32 byte = code < 4 ? (s1 >> (8 * code)) : (s0 >> (8 * (code - 4)));
        r |= (byte & 0xffu) << (8 * i);
    }
    return r;
#endif
}

// ---------------- scale ------------------------------------------------------
__global__ __launch_bounds__(256) void scale_kernel(
    const float* __restrict__ x, float* __restrict__ srow)   // srow = max/127
{
    __shared__ float red[256];
    const int lat = blockIdx.x, b = blockIdx.y, tid = threadIdx.x;
    float mx = 0.f;
    for (int c = 0; c < CIN; ++c) {
        const float* row = x + ((size_t)(b * CIN + c) * NLAT + lat) * NLON;
        for (int l = tid; l < NLON; l += 256)
            mx = fmaxf(mx, fabsf(row[l]));
    }
    red[tid] = mx;
    __syncthreads();
    for (int s = 128; s > 0; s >>= 1) {
        if (tid < s) red[tid] = fmaxf(red[tid], red[tid + s]);
        __syncthreads();
    }
    if (tid == 0) srow[b * NLAT + lat] = fmaxf(red[0], 1e-20f) * (1.f / 127.f);
}

// ---------------- prep ------------------------------------------------------
__global__ __launch_bounds__(256) void prep_kernel(
    const float* __restrict__ x, const float* __restrict__ weight,
    const float* __restrict__ psi_vals, const int* __restrict__ psi_lat_in,
    const int* __restrict__ psi_lon_in, const float* __restrict__ srow,
    u8* __restrict__ xT8, f16* __restrict__ wT, int4* __restrict__ meta)
{
    const int bid = blockIdx.x, tid = threadIdx.x;
    if (bid < G0) {                           // x -> int8 lines: 4 lon x 8 c per thread
        const int u = bid * 256 + tid;
        if (u >= U0) return;
        const int ch   = u & 7;               // c-octet 0..7
        const int v    = u >> 3;
        const int lon4 = v % 90;
        const int w    = v / 90;
        const int lat  = w % NLAT;
        const int b    = w / NLAT;
        const int lon0 = lon4 * 4;
        const float qs = 1.0f / srow[b * NLAT + lat];     // 127/max
        const float* src = x + ((size_t)(b * CIN + ch * 8) * NLAT + lat) * NLON + lon0;
        f32x4 L[8];
#pragma unroll
        for (int j = 0; j < 8; ++j)
            L[j] = *(const f32x4*)&src[(size_t)j * NLAT * NLON];
        u8* xrow = xT8 + (size_t)(b * NLAT + lat) * ROWB8;
        // octet ch -> slot (ch&3): bytes 0..7 = c q*8.., bytes 8..15 = c 32+q*8..
        const u32 ub = (u32)((ch & 3) * 16 + (ch >> 2) * 8);
#pragma unroll
        for (int dl = 0; dl < 4; ++dl) {
            u32 d0 = 0, d1 = 0;
#pragma unroll
            for (int j = 0; j < 8; ++j) {
                float qf = __builtin_rintf(L[j][dl] * qs);
                qf = fminf(fmaxf(qf, -127.f), 127.f);
                u32 uq = (u32)(int)(qf + 128.f);          // q+128 in [1,255]
                if (j < 4) d0 |= uq << (8 * j);
                else       d1 |= uq << (8 * (j - 4));
            }
            u32 uoff = (u32)((lon0 + dl) * 64) + ub;
            u32 a = uoff ^ ((uoff >> 3) & 0x70u);         // baked slot swizzle
            uint2 st = {d0, d1};
            *(uint2*)(xrow + a) = st;                     // bit3 untouched by swz
        }
        return;
    }
    if (bid < G0 + G1) {                      // wT[k][f][c] = W[f][c][k]  (f16)
        const int e = (bid - G0) * 256 + tid;
        if (e < KS * 4096) {
            int c = e & 63, f = (e >> 6) & 63, k = e >> 12;
            wT[e] = (f16)weight[((size_t)(f * 64 + c)) * KS + k];
        }
        return;
    }
    {                                         // tap metadata, [k][lat][t]
        const int e = (bid - G0 - G1) * 256 + tid;
        if (e < NMETA) {
            int lat = (e / NPER) % NLAT;
            int li  = psi_lat_in[e];
            float psi = psi_vals[e];
            // psi * s(b,row) pre-packed as f16x2 broadcast pair, per batch
            u32 h0 = (u32)__builtin_bit_cast(u16, (f16)(psi * srow[0 * NLAT + li]));
            u32 h1 = (u32)__builtin_bit_cast(u16, (f16)(psi * srow[1 * NLAT + li]));
            int lonb = psi_lon_in[e] << 6;    // lon*64 B
            int4 m;
            m.x = (int)(h0 | (h0 << 16));                  // b=0 multiplier
            m.y = (li - lat + 1) * SLOTB + lonb;           // slot base + lon off
            m.z = lonb;                                    // wrap compare
            m.w = (int)(h1 | (h1 << 16));                  // b=1 multiplier
            meta[e] = m;
        }
    }
}

// ---------------- main ------------------------------------------------------
__global__ __launch_bounds__(768, 6) void disco_main(
    const u8* __restrict__ xT8, const f16* __restrict__ wT,
    const int4* __restrict__ meta, const float* __restrict__ bias,
    float* __restrict__ out)
{
    extern __shared__ char xs[];              // [slot 3 x 23552][lon 360][64B line]
    const int tid  = threadIdx.x;
    const int lane = tid & 63, wave = tid >> 6;   // 12 waves
    const int pn   = lane & 15, q = lane >> 4;
    const int half2 = blockIdx.x, lat = blockIdx.y, b = blockIdx.z;

    const int tile = half2 * 12 + wave;       // 0..11 | 12..23 (23 = dummy)
    const bool act = tile < 23;               // wave-uniform
    const int p  = tile * 16 + pn;            // <= 367; >=360 masked at store
    const int pl = p >= NLON ? p - NLON : p;
    const u32 plq  = (u32)((pl << 6) + (q << 4));   // p*64 + q*16
    const u32 plqm = plq - (u32)ROWB8;              // wrapped variant
    const u32 thr  = (u32)((NLON - pl) << 6);       // wrap iff lon*64 >= thr

    const int rr0 = lat > 0 ? lat - 1 : 0;
    const int rr2 = lat < NLAT - 1 ? lat + 1 : NLAT - 1;

    // stage: 3 rows x 1440 16B units into padded slots
    {
        const size_t bb = (size_t)b * NLAT;
        const char* s0 = (const char*)xT8 + (bb + rr0) * ROWB8;
        const char* s1 = (const char*)xT8 + (bb + lat) * ROWB8;
        const char* s2 = (const char*)xT8 + (bb + rr2) * ROWB8;
        for (int i = tid; i < 1440; i += 768) {
            *(u32x4*)&xs[i * 16]             = *(const u32x4*)&s0[i * 16];
            *(u32x4*)&xs[SLOTB + i * 16]     = *(const u32x4*)&s1[i * 16];
            *(u32x4*)&xs[2 * SLOTB + i * 16] = *(const u32x4*)&s2[i * 16];
        }
    }
    __syncthreads();                          // the ONLY barrier

    f32x4 D[4];
#pragma unroll
    for (int ft = 0; ft < 4; ++ft) D[ft] = (f32x4){0.f, 0.f, 0.f, 0.f};

    const u32 C64 = 0x64646464u;
    const u32 BB  = 0xE480E480u;              // f16x2 of -1152
    const f16x8 B8 = __builtin_bit_cast(f16x8, (u32x4){BB, BB, BB, BB});
    const bool bsel = (b != 0);

    if (act) {
        for (int k = 0; k < KS; ++k) {
            f16x8 acc0 = (f16x8){0, 0, 0, 0, 0, 0, 0, 0};   // c = q*8+j
            f16x8 acc1 = (f16x8){0, 0, 0, 0, 0, 0, 0, 0};   // c = 32+q*8+j
            const int4* mp = meta + (k * NLAT + lat) * NPER;
#pragma unroll
            for (int tg = 0; tg < NPER; tg += 8) {
                int4 m[8];
#pragma unroll
                for (int j = 0; j < 8; ++j) m[j] = mp[tg + j];  // uniform -> s_load

                u32 a[8];
#pragma unroll
                for (int j = 0; j < 8; ++j) {
                    u32 ad = ((u32)m[j].z >= thr) ? plqm : plq; // cmp + cndmask
                    u32 t  = (u32)m[j].y + ad;
                    a[j]   = t ^ ((t >> 3) & 0x70u);            // slot swizzle
                }
                u32x4 xv[8];                                    // 8 b128 in flight
#pragma unroll
                for (int j = 0; j < 8; ++j)
                    xv[j] = *(const u32x4*)(xs + a[j]);
#pragma unroll
                for (int j = 0; j < 8; ++j) {
                    const u32 mm = bsel ? (u32)m[j].w : (u32)m[j].x;
                    const f16x8 mh = __builtin_bit_cast(f16x8, (u32x4){mm, mm, mm, mm});
                    u32 p0 = bperm(C64, xv[j][0], SEL_LO);      // (1024+u0,1024+u1)
                    u32 p1 = bperm(C64, xv[j][0], SEL_HI);
                    u32 p2 = bperm(C64, xv[j][1], SEL_LO);
                    u32 p3 = bperm(C64, xv[j][1], SEL_HI);
                    f16x8 v0 = __builtin_bit_cast(f16x8, (u32x4){p0, p1, p2, p3});
                    acc0 += mh * (v0 + B8);                     // pk_add + pk_fma
                    u32 p4 = bperm(C64, xv[j][2], SEL_LO);
                    u32 p5 = bperm(C64, xv[j][2], SEL_HI);
                    u32 p6 = bperm(C64, xv[j][3], SEL_LO);
                    u32 p7 = bperm(C64, xv[j][3], SEL_HI);
                    f16x8 v1 = __builtin_bit_cast(f16x8, (u32x4){p4, p5, p6, p7});
                    acc1 += mh * (v1 + B8);
                }
            }

            // A frags: wT[k][f][c], f = ft*16 + pn
            f16x8 Af0[4], Af1[4];
            const f16* wk = wT + (size_t)k * 4096 + q * 8;
#pragma unroll
            for (int ft = 0; ft < 4; ++ft) {
                Af0[ft] = *(const f16x8*)&wk[(ft * 16 + pn) * 64];        // c = q*8+j
                Af1[ft] = *(const f16x8*)&wk[32 + (ft * 16 + pn) * 64];   // +32
            }
#pragma unroll
            for (int ft = 0; ft < 4; ++ft) {
                D[ft] = __builtin_amdgcn_mfma_f32_16x16x32_f16(Af0[ft], acc0, D[ft], 0, 0, 0);
                D[ft] = __builtin_amdgcn_mfma_f32_16x16x32_f16(Af1[ft], acc1, D[ft], 0, 0, 0);
            }
        }
    }

    // epilogue: D[m=f][n=p], lane: col = pn, rows (lane>>4)*4 + r
    if (act && p < NLON) {
#pragma unroll
        for (int ft = 0; ft < 4; ++ft)
#pragma unroll
            for (int r = 0; r < 4; ++r) {
                const int f = ft * 16 + q * 4 + r;
                out[((size_t)(b * COUT + f) * NLAT + lat) * NLON + p] = D[ft][r] + bias[f];
            }
    }
}

extern "C" void kernel_launch(void* const* d_in, const int* in_sizes, int n_in,
                              void* d_out, int out_size, void* d_ws, size_t ws_size,
                              hipStream_t stream) {
    const float* x          = (const float*)d_in[0];
    const float* psi_vals   = (const float*)d_in[1];
    const float* weight     = (const float*)d_in[2];
    const float* bias       = (const float*)d_in[3];
    const int*   psi_lat_in = (const int*)d_in[6];
    const int*   psi_lon_in = (const int*)d_in[7];
    float* out = (float*)d_out;

    u8*    xT8  = (u8*)d_ws;
    f16*   wT   = (f16*)((char*)d_ws + XT8_BYTES);
    int4*  meta = (int4*)((char*)d_ws + XT8_BYTES + WT_BYTES);
    float* srow = (float*)((char*)d_ws + XT8_BYTES + WT_BYTES + META_BYTES);

    (void)hipFuncSetAttribute((const void*)disco_main,
                              hipFuncAttributeMaxDynamicSharedMemorySize, XS_BYTES);

    scale_kernel<<<dim3(NLAT, NB), 256, 0, stream>>>(x, srow);
    prep_kernel<<<dim3(G0 + G1 + G2), 256, 0, stream>>>(
        x, weight, psi_vals, psi_lat_in, psi_lon_in, srow, xT8, wT, meta);
    disco_main<<<dim3(2, NLAT, NB), 768, XS_BYTES, stream>>>(
        xT8, wT, meta, bias, out);
}

// Round 10
// 261.060 us; speedup vs baseline: 1.7660x; 1.7660x over previous
//
#include <hip/hip_runtime.h>

// DISCO S2 conv, round 16 = round 15 (int8, passed absmax 7.8e-3) minus its
// two perf bugs:
//  (1) __launch_bounds__(768,6) forced VGPR=40 -> ~1GB scratch spill traffic
//      (WRITE_SIZE 1.04GB). Now (768,3), tap groups 8->4 to keep VGPR <= ~84
//      so LDS (70.7KB) still allows 2 blocks/CU.
//  (2) swizzle &0x70 polluted bank bit 6 (lon bit in the 64B-line layout) and
//      360%16!=0 broke it at the wrap -> 3.6M bank conflicts. Now &0x30:
//      slot bits 4,5 ^= lon bits 1,2; bank bits (lon0, q1^lon2, q0^lon1)
//      bijective per 8 consecutive lons; 360%8==0 -> wrap-safe.
// Dequant unchanged: u8(=q+128) -> f16 via v_perm (0x6400|u = 1024+u), pk_add
// -1152, pk_fma with psi*s f16x2 broadcast from meta; acc feeds mfma f16.

#define NB    2
#define CIN   64
#define COUT  64
#define KS    9
#define NLAT  181
#define NLON  360
#define NPER  24

typedef _Float16 f16;
typedef _Float16 f16x8 __attribute__((ext_vector_type(8)));
typedef float    f32x4 __attribute__((ext_vector_type(4)));
typedef unsigned int u32;
typedef unsigned short u16;
typedef unsigned char u8;
typedef u32 u32x4 __attribute__((ext_vector_type(4)));

#define ROWB8     23040                                   // 360*64 B per lat row
#define SLOTB     23552                                   // padded LDS slot stride
#define XT8_BYTES ((size_t)NB * NLAT * ROWB8)             // 8,340,480
#define WT_BYTES  (KS * 64 * 64 * 2)                      // 73,728
#define NMETA     (KS * NLAT * NPER)                      // 39,096
#define META_BYTES ((size_t)NMETA * 16)
#define XS_BYTES  (3 * SLOTB)                             // 70,656 B LDS

#define U0  (NB * NLAT * 90 * 8)                          // 260,640 threads
#define G0  ((U0 + 255) / 256)                            // 1019
#define G1  ((KS * 4096 + 255) / 256)                     // 144
#define G2  ((NMETA + 255) / 256)                         // 153

#define SEL_LO 0x05010400u
#define SEL_HI 0x05030402u

__device__ __forceinline__ u32 bperm(u32 s0, u32 s1, u32 sel) {
#if __has_builtin(__builtin_amdgcn_perm)
    return __builtin_amdgcn_perm(s0, s1, sel);
#else
    u32 r = 0;
#pragma unroll
    for (int i = 0; i < 4; ++i) {
        u32 code = (sel >> (8 * i)) & 0xffu;
        u32 byte = code < 4 ? (s1 >> (8 * code)) : (s0 >> (8 * (code - 4)));
        r |= (byte & 0xffu) << (8 * i);
    }
    return r;
#endif
}

// ---------------- scale ------------------------------------------------------
__global__ __launch_bounds__(256) void scale_kernel(
    const float* __restrict__ x, float* __restrict__ srow)   // srow = max/127
{
    __shared__ float red[256];
    const int lat = blockIdx.x, b = blockIdx.y, tid = threadIdx.x;
    float mx = 0.f;
    for (int c = 0; c < CIN; ++c) {
        const float* row = x + ((size_t)(b * CIN + c) * NLAT + lat) * NLON;
        for (int l = tid; l < NLON; l += 256)
            mx = fmaxf(mx, fabsf(row[l]));
    }
    red[tid] = mx;
    __syncthreads();
    for (int s = 128; s > 0; s >>= 1) {
        if (tid < s) red[tid] = fmaxf(red[tid], red[tid + s]);
        __syncthreads();
    }
    if (tid == 0) srow[b * NLAT + lat] = fmaxf(red[0], 1e-20f) * (1.f / 127.f);
}

// ---------------- prep ------------------------------------------------------
__global__ __launch_bounds__(256) void prep_kernel(
    const float* __restrict__ x, const float* __restrict__ weight,
    const float* __restrict__ psi_vals, const int* __restrict__ psi_lat_in,
    const int* __restrict__ psi_lon_in, const float* __restrict__ srow,
    u8* __restrict__ xT8, f16* __restrict__ wT, int4* __restrict__ meta)
{
    const int bid = blockIdx.x, tid = threadIdx.x;
    if (bid < G0) {                           // x -> int8 lines: 4 lon x 8 c per thread
        const int u = bid * 256 + tid;
        if (u >= U0) return;
        const int ch   = u & 7;               // c-octet 0..7
        const int v    = u >> 3;
        const int lon4 = v % 90;
        const int w    = v / 90;
        const int lat  = w % NLAT;
        const int b    = w / NLAT;
        const int lon0 = lon4 * 4;
        const float qs = 1.0f / srow[b * NLAT + lat];     // 127/max
        const float* src = x + ((size_t)(b * CIN + ch * 8) * NLAT + lat) * NLON + lon0;
        f32x4 L[8];
#pragma unroll
        for (int j = 0; j < 8; ++j)
            L[j] = *(const f32x4*)&src[(size_t)j * NLAT * NLON];
        u8* xrow = xT8 + (size_t)(b * NLAT + lat) * ROWB8;
        // octet ch -> slot (ch&3): bytes 0..7 = c q*8.., bytes 8..15 = c 32+q*8..
        const u32 ub = (u32)((ch & 3) * 16 + (ch >> 2) * 8);
#pragma unroll
        for (int dl = 0; dl < 4; ++dl) {
            u32 d0 = 0, d1 = 0;
#pragma unroll
            for (int j = 0; j < 8; ++j) {
                float qf = __builtin_rintf(L[j][dl] * qs);
                qf = fminf(fmaxf(qf, -127.f), 127.f);
                u32 uq = (u32)(int)(qf + 128.f);          // q+128 in [1,255]
                if (j < 4) d0 |= uq << (8 * j);
                else       d1 |= uq << (8 * (j - 4));
            }
            u32 uoff = (u32)((lon0 + dl) * 64) + ub;
            u32 a = uoff ^ ((uoff >> 3) & 0x30u);         // slot ^= lon bits 1,2
            uint2 st = {d0, d1};
            *(uint2*)(xrow + a) = st;                     // bit3 (half-sel) untouched
        }
        return;
    }
    if (bid < G0 + G1) {                      // wT[k][f][c] = W[f][c][k]  (f16)
        const int e = (bid - G0) * 256 + tid;
        if (e < KS * 4096) {
            int c = e & 63, f = (e >> 6) & 63, k = e >> 12;
            wT[e] = (f16)weight[((size_t)(f * 64 + c)) * KS + k];
        }
        return;
    }
    {                                         // tap metadata, [k][lat][t]
        const int e = (bid - G0 - G1) * 256 + tid;
        if (e < NMETA) {
            int lat = (e / NPER) % NLAT;
            int li  = psi_lat_in[e];
            float psi = psi_vals[e];
            // psi * s(b,row) pre-packed as f16x2 broadcast pair, per batch
            u32 h0 = (u32)__builtin_bit_cast(u16, (f16)(psi * srow[0 * NLAT + li]));
            u32 h1 = (u32)__builtin_bit_cast(u16, (f16)(psi * srow[1 * NLAT + li]));
            int lonb = psi_lon_in[e] << 6;    // lon*64 B
            int4 m;
            m.x = (int)(h0 | (h0 << 16));                  // b=0 multiplier
            m.y = (li - lat + 1) * SLOTB + lonb;           // slot base + lon off
            m.z = lonb;                                    // wrap compare
            m.w = (int)(h1 | (h1 << 16));                  // b=1 multiplier
            meta[e] = m;
        }
    }
}

// ---------------- main ------------------------------------------------------
__global__ __launch_bounds__(768, 3) void disco_main(
    const u8* __restrict__ xT8, const f16* __restrict__ wT,
    const int4* __restrict__ meta, const float* __restrict__ bias,
    float* __restrict__ out)
{
    extern __shared__ char xs[];              // [slot 3 x 23552][lon 360][64B line]
    const int tid  = threadIdx.x;
    const int lane = tid & 63, wave = tid >> 6;   // 12 waves
    const int pn   = lane & 15, q = lane >> 4;
    const int half2 = blockIdx.x, lat = blockIdx.y, b = blockIdx.z;

    const int tile = half2 * 12 + wave;       // 0..11 | 12..23 (23 = dummy)
    const bool act = tile < 23;               // wave-uniform
    const int p  = tile * 16 + pn;            // <= 367; >=360 masked at store
    const int pl = p >= NLON ? p - NLON : p;
    const u32 plq  = (u32)((pl << 6) + (q << 4));   // p*64 + q*16
    const u32 plqm = plq - (u32)ROWB8;              // wrapped variant
    const u32 thr  = (u32)((NLON - pl) << 6);       // wrap iff lon*64 >= thr

    const int rr0 = lat > 0 ? lat - 1 : 0;
    const int rr2 = lat < NLAT - 1 ? lat + 1 : NLAT - 1;

    // stage: 3 rows x 1440 16B units into padded slots
    {
        const size_t bb = (size_t)b * NLAT;
        const char* s0 = (const char*)xT8 + (bb + rr0) * ROWB8;
        const char* s1 = (const char*)xT8 + (bb + lat) * ROWB8;
        const char* s2 = (const char*)xT8 + (bb + rr2) * ROWB8;
        for (int i = tid; i < 1440; i += 768) {
            *(u32x4*)&xs[i * 16]             = *(const u32x4*)&s0[i * 16];
            *(u32x4*)&xs[SLOTB + i * 16]     = *(const u32x4*)&s1[i * 16];
            *(u32x4*)&xs[2 * SLOTB + i * 16] = *(const u32x4*)&s2[i * 16];
        }
    }
    __syncthreads();                          // the ONLY barrier

    f32x4 D[4];
#pragma unroll
    for (int ft = 0; ft < 4; ++ft) D[ft] = (f32x4){0.f, 0.f, 0.f, 0.f};

    const u32 C64 = 0x64646464u;
    const u32 BB  = 0xE480E480u;              // f16x2 of -1152
    const f16x8 B8 = __builtin_bit_cast(f16x8, (u32x4){BB, BB, BB, BB});
    const bool bsel = (b != 0);

    if (act) {
        for (int k = 0; k < KS; ++k) {
            f16x8 acc0 = (f16x8){0, 0, 0, 0, 0, 0, 0, 0};   // c = q*8+j
            f16x8 acc1 = (f16x8){0, 0, 0, 0, 0, 0, 0, 0};   // c = 32+q*8+j
            const int4* mp = meta + (k * NLAT + lat) * NPER;
#pragma unroll
            for (int tg = 0; tg < NPER; tg += 4) {
                int4 m[4];
#pragma unroll
                for (int j = 0; j < 4; ++j) m[j] = mp[tg + j];  // uniform -> s_load

                u32 a[4];
#pragma unroll
                for (int j = 0; j < 4; ++j) {
                    u32 ad = ((u32)m[j].z >= thr) ? plqm : plq; // cmp + cndmask
                    u32 t  = (u32)m[j].y + ad;
                    a[j]   = t ^ ((t >> 3) & 0x30u);            // slot swizzle
                }
                u32x4 xv[4];                                    // 4 b128 in flight
#pragma unroll
                for (int j = 0; j < 4; ++j)
                    xv[j] = *(const u32x4*)(xs + a[j]);
#pragma unroll
                for (int j = 0; j < 4; ++j) {
                    const u32 mm = bsel ? (u32)m[j].w : (u32)m[j].x;
                    const f16x8 mh = __builtin_bit_cast(f16x8, (u32x4){mm, mm, mm, mm});
                    u32 p0 = bperm(C64, xv[j][0], SEL_LO);      // (1024+u0,1024+u1)
                    u32 p1 = bperm(C64, xv[j][0], SEL_HI);
                    u32 p2 = bperm(C64, xv[j][1], SEL_LO);
                    u32 p3 = bperm(C64, xv[j][1], SEL_HI);
                    f16x8 v0 = __builtin_bit_cast(f16x8, (u32x4){p0, p1, p2, p3});
                    acc0 += mh * (v0 + B8);                     // pk_add + pk_fma
                    u32 p4 = bperm(C64, xv[j][2], SEL_LO);
                    u32 p5 = bperm(C64, xv[j][2], SEL_HI);
                    u32 p6 = bperm(C64, xv[j][3], SEL_LO);
                    u32 p7 = bperm(C64, xv[j][3], SEL_HI);
                    f16x8 v1 = __builtin_bit_cast(f16x8, (u32x4){p4, p5, p6, p7});
                    acc1 += mh * (v1 + B8);
                }
            }

            // A frags: wT[k][f][c], f = ft*16 + pn
            f16x8 Af0[4], Af1[4];
            const f16* wk = wT + (size_t)k * 4096 + q * 8;
#pragma unroll
            for (int ft = 0; ft < 4; ++ft) {
                Af0[ft] = *(const f16x8*)&wk[(ft * 16 + pn) * 64];        // c = q*8+j
                Af1[ft] = *(const f16x8*)&wk[32 + (ft * 16 + pn) * 64];   // +32
            }
#pragma unroll
            for (int ft = 0; ft < 4; ++ft) {
                D[ft] = __builtin_amdgcn_mfma_f32_16x16x32_f16(Af0[ft], acc0, D[ft], 0, 0, 0);
                D[ft] = __builtin_amdgcn_mfma_f32_16x16x32_f16(Af1[ft], acc1, D[ft], 0, 0, 0);
            }
        }
    }

    // epilogue: D[m=f][n=p], lane: col = pn, rows (lane>>4)*4 + r
    if (act && p < NLON) {
#pragma unroll
        for (int ft = 0; ft < 4; ++ft)
#pragma unroll
            for (int r = 0; r < 4; ++r) {
                const int f = ft * 16 + q * 4 + r;
                out[((size_t)(b * COUT + f) * NLAT + lat) * NLON + p] = D[ft][r] + bias[f];
            }
    }
}

extern "C" void kernel_launch(void* const* d_in, const int* in_sizes, int n_in,
                              void* d_out, int out_size, void* d_ws, size_t ws_size,
                              hipStream_t stream) {
    const float* x          = (const float*)d_in[0];
    const float* psi_vals   = (const float*)d_in[1];
    const float* weight     = (const float*)d_in[2];
    const float* bias       = (const float*)d_in[3];
    const int*   psi_lat_in = (const int*)d_in[6];
    const int*   psi_lon_in = (const int*)d_in[7];
    float* out = (float*)d_out;

    u8*    xT8  = (u8*)d_ws;
    f16*   wT   = (f16*)((char*)d_ws + XT8_BYTES);
    int4*  meta = (int4*)((char*)d_ws + XT8_BYTES + WT_BYTES);
    float* srow = (float*)((char*)d_ws + XT8_BYTES + WT_BYTES + META_BYTES);

    (void)hipFuncSetAttribute((const void*)disco_main,
                              hipFuncAttributeMaxDynamicSharedMemorySize, XS_BYTES);

    scale_kernel<<<dim3(NLAT, NB), 256, 0, stream>>>(x, srow);
    prep_kernel<<<dim3(G0 + G1 + G2), 256, 0, stream>>>(
        x, weight, psi_vals, psi_lat_in, psi_lon_in, srow, xT8, wT, meta);
    disco_main<<<dim3(2, NLAT, NB), 768, XS_BYTES, stream>>>(
        xT8, wT, meta, bias, out);
}

// Round 11
// 190.391 us; speedup vs baseline: 2.4215x; 1.3712x over previous
//
#include <hip/hip_runtime.h>

// DISCO S2 conv, round 17: revert to the session champion (round-0 baseline,
// 190.65/191.7 us measured twice). Ten structural variants (merged c-halves,
// meta software-pipelining, global/LDS dual-pipe, coalesced prep, fp8, int8)
// all tied (108 us main invariant) or regressed; int8 fixed its spills and
// bank conflicts but is dequant-VALU-bound at 142 us + 35 us extra dispatch
// overhead. The f16 gather floor (~70 us DS-pipe) plus ~38 us dependency
// bubbles has resisted every scheduling attack; the ~83 us non-main residual
// is harness-fixed (prep-insensitive, round-13 isolation).
// prep (one fat kernel, 4370x256): x -> xT f16 [b][h][lat][lon][oct^((lon>>1)&3)][8c]
//   (1 f16x8 per thread: 8 strided coalesced loads, contiguous full-line stores);
//   weight -> wT f16 [k][f][c]; taps -> meta int4 [k][lat][t] {psi_pk, slot*ROWB+lon*64, lon*64, 0}.
// main: 768-thr wgs (12 waves x one 16-p tile), 69KB LDS -> 2 wg/CU = 24 waves/CU = 6/SIMD.
//   Grid x in {0,1}: x=0 -> tiles 0..11, x=1 -> tiles 12..22 (+1 dummy wave, skips gather).
//   Per c-half: linear-stage 3 rows; per k: meta via s_load (R4 path), taps in groups of 8
//   (8 ds_read_b128 in flight), 6-VALU addressing, pk_fma f16 into B-frag, 4x mfma 16x16x32_f16.

#define NB    2
#define CIN   64
#define COUT  64
#define KS    9
#define NLAT  181
#define NLON  360
#define NPER  24

typedef _Float16 f16;
typedef _Float16 f16x8 __attribute__((ext_vector_type(8)));
typedef float    f32x4 __attribute__((ext_vector_type(4)));
typedef unsigned int u32;
typedef unsigned short u16;
typedef u32 u32x4 __attribute__((ext_vector_type(4)));

#define ROWB      23040                                   // 360*32*2 B per slot row
#define XT_BYTES  ((size_t)NB * 2 * NLAT * NLON * 32 * 2) // 16,680,960
#define WT_BYTES  (KS * 64 * 64 * 2)                      // 73,728
#define NMETA     (KS * NLAT * NPER)                      // 39,096
#define XS_BYTES  (3 * ROWB)                              // 69,120 B LDS

#define U0  (NB * 2 * 4 * NLAT * NLON)                    // 1,042,560 f16x8 units
#define G0  ((U0 + 255) / 256)                            // 4073
#define G1  ((KS * 4096 + 255) / 256)                     // 144
#define G2  ((NMETA + 255) / 256)                         // 153

// ---------------- prep ------------------------------------------------------
__global__ __launch_bounds__(256) void prep_kernel(
    const float* __restrict__ x, const float* __restrict__ weight,
    const float* __restrict__ psi_vals, const int* __restrict__ psi_lat_in,
    const int* __restrict__ psi_lon_in,
    f16* __restrict__ xT, f16* __restrict__ wT, int4* __restrict__ meta)
{
    const int bid = blockIdx.x, tid = threadIdx.x;
    if (bid < G0) {                           // x transpose, 1 f16x8 per thread
        const int u = bid * 256 + tid;
        if (u >= U0) return;
        const int oct = u & 3;
        const int v   = u >> 2;
        const int lon = v % NLON;
        const int w   = v / NLON;
        const int lat = w % NLAT;
        const int z   = w / NLAT;             // z = b*2 + h
        const int h   = z & 1, b = z >> 1;
        const float* src = x + ((size_t)(b * CIN + h * 32 + oct * 8) * NLAT + lat) * NLON + lon;
        f16x8 vv;
#pragma unroll
        for (int j = 0; j < 8; ++j)
            vv[j] = (f16)src[(size_t)j * NLAT * NLON];    // 8 independent loads
        const int op = oct ^ ((lon >> 1) & 3);            // baked bank swizzle
        *(f16x8*)&xT[(((size_t)z * NLAT + lat) * NLON + lon) * 32 + op * 8] = vv;
        return;
    }
    if (bid < G0 + G1) {                      // wT[k][f][c] = W[f][c][k]
        const int e = (bid - G0) * 256 + tid;
        if (e < KS * 4096) {
            int c = e & 63, f = (e >> 6) & 63, k = e >> 12;
            wT[e] = (f16)weight[((size_t)(f * 64 + c)) * KS + k];
        }
        return;
    }
    {                                         // packed tap metadata, [k][lat][t] order
        const int e = (bid - G0 - G1) * 256 + tid;
        if (e < NMETA) {
            int lat = (e / NPER) % NLAT;
            f16 pvh = (f16)psi_vals[e];
            u32 pb = (u32)__builtin_bit_cast(u16, pvh);
            int lonb = psi_lon_in[e] << 6;
            int4 m;
            m.x = (int)((pb << 16) | pb);
            m.y = (psi_lat_in[e] - lat + 1) * ROWB + lonb;  // combined byte base
            m.z = lonb;                                     // for wrap compare
            m.w = 0;
            meta[e] = m;
        }
    }
}

// ---------------- main ------------------------------------------------------
__global__ __launch_bounds__(768, 6) void disco_main(
    const f16* __restrict__ xT, const f16* __restrict__ wT,
    const int4* __restrict__ meta, const float* __restrict__ bias,
    float* __restrict__ out)
{
    extern __shared__ char xs[];              // [slot 3][lon 360][32c swizzled]
    const int tid  = threadIdx.x;
    const int lane = tid & 63, wave = tid >> 6;   // 12 waves
    const int pn   = lane & 15, q = lane >> 4;
    const int half2 = blockIdx.x, lat = blockIdx.y, b = blockIdx.z;

    const int tile = half2 * 12 + wave;       // 0..11 | 12..23 (23 = dummy)
    const bool act = tile < 23;               // wave-uniform
    const int p  = tile * 16 + pn;            // <= 367; >=360 masked at store
    const int pl = p >= NLON ? p - NLON : p;
    const u32 plq  = (u32)((pl << 6) + (q << 4)); // p*64 + q*16
    const u32 plqm = plq - (u32)ROWB;             // wrapped variant
    const u32 thr  = (u32)((NLON - pl) << 6);     // wrap iff lon*64 >= thr

    int rr0 = lat > 0 ? lat - 1 : 0;
    int rr2 = lat < NLAT - 1 ? lat + 1 : NLAT - 1;

    f32x4 D[4];
#pragma unroll
    for (int ft = 0; ft < 4; ++ft) D[ft] = (f32x4){0.f, 0.f, 0.f, 0.f};

    for (int h = 0; h < 2; ++h) {
        __syncthreads();                      // previous-half readers done
        {
            const size_t hb = (size_t)(b * 2 + h) * NLAT;
            const f16* s0 = xT + (hb + rr0) * NLON * 32;
            const f16* s1 = xT + (hb + lat) * NLON * 32;
            const f16* s2 = xT + (hb + rr2) * NLON * 32;
            for (int i = tid; i < 1440; i += 768) {
                *(f16x8*)&xs[i * 16]             = *(const f16x8*)&s0[i * 8];
                *(f16x8*)&xs[ROWB + i * 16]      = *(const f16x8*)&s1[i * 8];
                *(f16x8*)&xs[2 * ROWB + i * 16]  = *(const f16x8*)&s2[i * 8];
            }
        }
        __syncthreads();

        if (act) {
            for (int k = 0; k < KS; ++k) {
                f16x8 acc = (f16x8){0, 0, 0, 0, 0, 0, 0, 0};
                const int4* mp = meta + (k * NLAT + lat) * NPER;
#pragma unroll
                for (int tg = 0; tg < NPER; tg += 8) {
                    int4 m[8];
#pragma unroll
                    for (int j = 0; j < 8; ++j) m[j] = mp[tg + j];  // uniform -> s_load

                    u32 addr[8];
#pragma unroll
                    for (int j = 0; j < 8; ++j) {
                        u32 ad = ((u32)m[j].z >= thr) ? plqm : plq; // cmp + cndmask
                        u32 a  = (u32)m[j].y + ad;
                        addr[j] = a ^ ((a >> 3) & 48u);             // bank swizzle
                    }
                    f16x8 xv[8];                                    // 8 b128 in flight
#pragma unroll
                    for (int j = 0; j < 8; ++j)
                        xv[j] = *(const f16x8*)(xs + addr[j]);
#pragma unroll
                    for (int j = 0; j < 8; ++j) {
                        u32 pk = (u32)m[j].x;
                        u32x4 pkv = {pk, pk, pk, pk};
                        acc += xv[j] * __builtin_bit_cast(f16x8, pkv); // v_pk_fma_f16
                    }
                }

                // A frags: wT[k][f][c], c = h*32 + q*8 + j, f = ft*16 + pn
                f16x8 Af[4];
                const f16* wk = wT + (size_t)k * 4096 + h * 32 + q * 8;
#pragma unroll
                for (int ft = 0; ft < 4; ++ft)
                    Af[ft] = *(const f16x8*)&wk[(ft * 16 + pn) * 64];
#pragma unroll
                for (int ft = 0; ft < 4; ++ft)
                    D[ft] = __builtin_amdgcn_mfma_f32_16x16x32_f16(Af[ft], acc, D[ft], 0, 0, 0);
            }
        }
    }

    // epilogue: D[m=f][n=p], lane: col = pn, rows (lane>>4)*4 + r
    if (act && p < NLON) {
#pragma unroll
        for (int ft = 0; ft < 4; ++ft)
#pragma unroll
            for (int r = 0; r < 4; ++r) {
                const int f = ft * 16 + q * 4 + r;
                out[((size_t)(b * COUT + f) * NLAT + lat) * NLON + p] = D[ft][r] + bias[f];
            }
    }
}

extern "C" void kernel_launch(void* const* d_in, const int* in_sizes, int n_in,
                              void* d_out, int out_size, void* d_ws, size_t ws_size,
                              hipStream_t stream) {
    const float* x          = (const float*)d_in[0];
    const float* psi_vals   = (const float*)d_in[1];
    const float* weight     = (const float*)d_in[2];
    const float* bias       = (const float*)d_in[3];
    const int*   psi_lat_in = (const int*)d_in[6];
    const int*   psi_lon_in = (const int*)d_in[7];
    float* out = (float*)d_out;

    f16*  xT   = (f16*)d_ws;
    f16*  wT   = (f16*)((char*)d_ws + XT_BYTES);
    int4* meta = (int4*)((char*)d_ws + XT_BYTES + WT_BYTES);

    (void)hipFuncSetAttribute((const void*)disco_main,
                              hipFuncAttributeMaxDynamicSharedMemorySize, XS_BYTES);

    prep_kernel<<<dim3(G0 + G1 + G2), 256, 0, stream>>>(
        x, weight, psi_vals, psi_lat_in, psi_lon_in, xT, wT, meta);
    disco_main<<<dim3(2, NLAT, NB), 768, XS_BYTES, stream>>>(
        xT, wT, meta, bias, out);
}